// Round 1
// baseline (407.661 us; speedup 1.0000x reference)
//
#include <hip/hip_runtime.h>
#include <stdint.h>
#include <stddef.h>

#define HDN 2048
#define NH 16
#define KVH 2
#define HDIM 128
#define BB 2
#define SS 2048
#define MTOT 4096   // BB*SS

typedef float f32x4 __attribute__((ext_vector_type(4)));
typedef short s16x8 __attribute__((ext_vector_type(8)));
typedef unsigned short u16;
typedef unsigned int u32;

__device__ __forceinline__ u16 f2b(float f) {
    u32 u = __builtin_bit_cast(u32, f);
    u += 0x7fffu + ((u >> 16) & 1u);
    return (u16)(u >> 16);
}

#define GLD_LDS16(src, dst) __builtin_amdgcn_global_load_lds( \
    (const __attribute__((address_space(1))) u32*)(src), \
    (__attribute__((address_space(3))) u32*)(dst), 16, 0, 0)

// ---------------- fp32 -> bf16 convert (8 elems/thread/iter) ----------------
__global__ void cvt_f32_bf16(const float* __restrict__ in, u16* __restrict__ out, int n8) {
    int stride = gridDim.x * blockDim.x;
    for (int idx = blockIdx.x * blockDim.x + threadIdx.x; idx < n8; idx += stride) {
        const float4* p = reinterpret_cast<const float4*>(in) + (size_t)idx * 2;
        float4 a = p[0], b = p[1];
        u16 u[8] = {f2b(a.x), f2b(a.y), f2b(a.z), f2b(a.w),
                    f2b(b.x), f2b(b.y), f2b(b.z), f2b(b.w)};
        reinterpret_cast<uint4*>(out)[idx] = *reinterpret_cast<uint4*>(u);
    }
}

// ---------------- GEMM: C[M,N] = A[M,K] * B[N,K]^T (+bias), fp32 out --------
// 128x128 tile, BK=32, 256 threads (4 waves, 2x2), 16x16x32 bf16 MFMA.
// LDS rows are 64B (4x16B slots); XOR swizzle slot^=((row>>1)&3) on both the
// staged global source and the ds_read offsets (linear LDS dest, rule 21).
template<bool HAS_BIAS>
__global__ __launch_bounds__(256) void gemm_bt(
    const u16* __restrict__ A, const u16* __restrict__ B,
    const float* __restrict__ bias, float* __restrict__ C,
    int N, int K)
{
    const int tid = threadIdx.x;
    const int lane = tid & 63;
    const int w = tid >> 6;
    const int wm = w >> 1, wn = w & 1;
    const int bm = blockIdx.y, bn = blockIdx.x;

    __shared__ u16 As[128 * 32];
    __shared__ u16 Bs[128 * 32];

    f32x4 acc[4][4];
#pragma unroll
    for (int i = 0; i < 4; i++)
#pragma unroll
        for (int j = 0; j < 4; j++)
            acc[i][j] = (f32x4){0.f, 0.f, 0.f, 0.f};

    int srow[2], scol[2], sdst[2];
#pragma unroll
    for (int i = 0; i < 2; i++) {
        int o = w * 128 + i * 64 + lane;      // 16B slot index in [0,512)
        int r = o >> 2, s = o & 3;
        srow[i] = r;
        scol[i] = (s ^ ((r >> 1) & 3)) * 8;   // pre-swizzled source col (elems)
        sdst[i] = (w * 128 + i * 64) * 8;     // wave-uniform dest (u16 units)
    }

    const u16* Ab = A + (size_t)bm * 128 * K;
    const u16* Bb = B + (size_t)bn * 128 * K;

    int a_off[4], b_off[4];
#pragma unroll
    for (int f = 0; f < 4; f++) {
        int ra = wm * 64 + f * 16 + (lane & 15);
        a_off[f] = ra * 64 + (((lane >> 4) ^ ((ra >> 1) & 3)) << 4);
        int rb = wn * 64 + f * 16 + (lane & 15);
        b_off[f] = rb * 64 + (((lane >> 4) ^ ((rb >> 1) & 3)) << 4);
    }

    const int kiters = K >> 5;
    for (int kt = 0; kt < kiters; kt++) {
        __syncthreads();
        const int k0 = kt * 32;
#pragma unroll
        for (int i = 0; i < 2; i++) {
            GLD_LDS16(Ab + (size_t)srow[i] * K + k0 + scol[i], As + sdst[i]);
            GLD_LDS16(Bb + (size_t)srow[i] * K + k0 + scol[i], Bs + sdst[i]);
        }
        __syncthreads();
        s16x8 af[4], bfv[4];
#pragma unroll
        for (int f = 0; f < 4; f++) {
            af[f]  = *reinterpret_cast<const s16x8*>((const char*)As + a_off[f]);
            bfv[f] = *reinterpret_cast<const s16x8*>((const char*)Bs + b_off[f]);
        }
#pragma unroll
        for (int mf = 0; mf < 4; mf++)
#pragma unroll
            for (int nf = 0; nf < 4; nf++)
                acc[mf][nf] = __builtin_amdgcn_mfma_f32_16x16x32_bf16(
                    af[mf], bfv[nf], acc[mf][nf], 0, 0, 0);
    }

#pragma unroll
    for (int nf = 0; nf < 4; nf++) {
        int col = bn * 128 + wn * 64 + nf * 16 + (lane & 15);
        float bv = HAS_BIAS ? bias[col] : 0.0f;
#pragma unroll
        for (int mf = 0; mf < 4; mf++) {
            int row0 = bm * 128 + wm * 64 + mf * 16 + ((lane >> 4) << 2);
#pragma unroll
            for (int r = 0; r < 4; r++)
                C[(size_t)(row0 + r) * N + col] = acc[mf][nf][r] + bv;
        }
    }
}

// ---------------- mRoPE: fp32 in [B*S][nheads*128] -> bf16 [B][nh][S][128] --
__global__ void rope_kernel(const float* __restrict__ pre,
                            const float* __restrict__ cosp,
                            const float* __restrict__ sinp,
                            u16* __restrict__ out, int nheads)
{
    int idx = blockIdx.x * blockDim.x + threadIdx.x; // d fastest (64), then h, then b*s
    int total = BB * SS * nheads * 64;
    if (idx >= total) return;
    int d = idx & 63;
    int h = (idx >> 6) % nheads;
    int bs = idx / (64 * nheads);
    int b = bs / SS, s = bs % SS;
    int stream = (d < 16) ? 0 : (d < 40 ? 1 : 2);   // MROPE_SECTION [16,24,24]
    size_t cbase = ((size_t)(stream * BB + b) * SS + s) * HDIM;
    float c1 = cosp[cbase + d],      s1 = sinp[cbase + d];
    float c2 = cosp[cbase + d + 64], s2 = sinp[cbase + d + 64];
    size_t qbase = (size_t)bs * (nheads * HDIM) + h * HDIM;
    float q1 = pre[qbase + d], q2 = pre[qbase + d + 64];
    float o1 = q1 * c1 - q2 * s1;   // rotate_half: [-x2, x1]
    float o2 = q2 * c2 + q1 * s2;
    size_t obase = (((size_t)b * nheads + h) * SS + s) * HDIM;
    out[obase + d]      = f2b(o1);
    out[obase + d + 64] = f2b(o2);
}

// ---------------- V: fp32 [B*S][KVH*128] -> bf16 V^T [B][KVH][128][S] -------
__global__ void vt_kernel(const float* __restrict__ Vpre, u16* __restrict__ Vt)
{
    __shared__ float tile[64][65];
    int st = blockIdx.x, dt = blockIdx.y, bk = blockIdx.z;
    int b = bk / KVH, kv = bk % KVH;
    int t = threadIdx.x;
    int r = t >> 2, c0 = (t & 3) * 16;
#pragma unroll
    for (int j = 0; j < 16; j++) {
        int s = st * 64 + r, d = dt * 64 + c0 + j;
        tile[r][c0 + j] = Vpre[(size_t)(b * SS + s) * (KVH * HDIM) + kv * HDIM + d];
    }
    __syncthreads();
#pragma unroll
    for (int j = 0; j < 16; j++) {
        int d = dt * 64 + r, s = st * 64 + c0 + j;
        Vt[((size_t)(b * KVH + kv) * HDIM + d) * SS + s] = f2b(tile[c0 + j][r]);
    }
}

// ---------------- Flash attention, causal, GQA ------------------------------
// grid (S/64, NH, B); 256 thr = 4 waves x 16 q-rows. KV tiles of 64.
__global__ __launch_bounds__(256) void attn_kernel(
    const u16* __restrict__ Qb,  // [B][NH][S][128]
    const u16* __restrict__ Kb,  // [B][KVH][S][128]
    const u16* __restrict__ Vt,  // [B][KVH][128][S]
    u16* __restrict__ AO)        // [B][S][NH*128]
{
    const int qt = blockIdx.x, h = blockIdx.y, b = blockIdx.z;
    const int kvh = h / (NH / KVH);
    const int tid = threadIdx.x, lane = tid & 63, w = tid >> 6;

    __shared__ u16 Ks[64 * 128];   // rows=kv (256B), 16 slots, swz slot^(kv&7)
    __shared__ u16 Vs[128 * 64];   // rows=d  (128B), 8 slots,  swz slot^(d&7)
    __shared__ u16 Ps[4][16 * 64]; // per-wave P, rows=q (128B), swz slot^(q&7)

    const int q0 = qt * 64 + w * 16;

    const u16* Qrow = Qb + (((size_t)b * NH + h) * SS + q0 + (lane & 15)) * HDIM;
    s16x8 qf[4];
#pragma unroll
    for (int kk = 0; kk < 4; kk++)
        qf[kk] = *reinterpret_cast<const s16x8*>(Qrow + kk * 32 + ((lane >> 4) * 8));

    f32x4 o_acc[8];
#pragma unroll
    for (int i = 0; i < 8; i++) o_acc[i] = (f32x4){0.f, 0.f, 0.f, 0.f};
    float m_run[4], l_run[4];
#pragma unroll
    for (int r = 0; r < 4; r++) { m_run[r] = -1e30f; l_run[r] = 0.0f; }

    const u16* Kbase = Kb + ((size_t)b * KVH + kvh) * SS * HDIM;
    const u16* Vbase = Vt + ((size_t)b * KVH + kvh) * HDIM * (size_t)SS;

    int k_r[4], k_c[4], v_r[4], v_c[4], sdst[4];
#pragma unroll
    for (int i = 0; i < 4; i++) {
        int o = w * 256 + i * 64 + lane;       // 16B slots in [0,1024)
        int r = o >> 4, s = o & 15;            // K tile: 16 slots/row
        k_r[i] = r; k_c[i] = (s ^ (r & 7)) * 8;
        int r2 = o >> 3, s2 = o & 7;           // V tile: 8 slots/row
        v_r[i] = r2; v_c[i] = (s2 ^ (r2 & 7)) * 8;
        sdst[i] = (w * 256 + i * 64) * 8;      // u16 units
    }
    const float scale = 0.08838834764831845f;  // 1/sqrt(128)
    const int ntiles = qt + 1;

    for (int kt = 0; kt < ntiles; kt++) {
        __syncthreads();
        const size_t kvoff = (size_t)kt * 64;
#pragma unroll
        for (int i = 0; i < 4; i++) {
            GLD_LDS16(Kbase + (kvoff + k_r[i]) * HDIM + k_c[i], Ks + sdst[i]);
            GLD_LDS16(Vbase + (size_t)v_r[i] * SS + kvoff + v_c[i], Vs + sdst[i]);
        }
        __syncthreads();

        // S = Q K^T  (16 q-rows x 64 kv)
        f32x4 sacc[4];
#pragma unroll
        for (int nf = 0; nf < 4; nf++) sacc[nf] = (f32x4){0.f, 0.f, 0.f, 0.f};
#pragma unroll
        for (int nf = 0; nf < 4; nf++) {
            int kvrow = nf * 16 + (lane & 15);
#pragma unroll
            for (int kk = 0; kk < 4; kk++) {
                int slot = kk * 4 + (lane >> 4);
                s16x8 kf = *reinterpret_cast<const s16x8*>(
                    (const char*)Ks + kvrow * 256 + ((slot ^ (kvrow & 7)) << 4));
                sacc[nf] = __builtin_amdgcn_mfma_f32_16x16x32_bf16(qf[kk], kf, sacc[nf], 0, 0, 0);
            }
        }

        // scale + causal mask + per-row max (rows live in 16-lane groups)
        int qrow[4];
#pragma unroll
        for (int r = 0; r < 4; r++) qrow[r] = q0 + ((lane >> 4) << 2) + r;
        float mt[4] = {-1e30f, -1e30f, -1e30f, -1e30f};
#pragma unroll
        for (int nf = 0; nf < 4; nf++) {
            int kv = kt * 64 + nf * 16 + (lane & 15);
#pragma unroll
            for (int r = 0; r < 4; r++) {
                float sv = sacc[nf][r] * scale;
                sv = (kv <= qrow[r]) ? sv : -1e30f;
                sacc[nf][r] = sv;
                mt[r] = fmaxf(mt[r], sv);
            }
        }
#pragma unroll
        for (int off = 1; off < 16; off <<= 1)
#pragma unroll
            for (int r = 0; r < 4; r++)
                mt[r] = fmaxf(mt[r], __shfl_xor(mt[r], off, 64));

        float alpha[4];
#pragma unroll
        for (int r = 0; r < 4; r++) {
            float mnew = fmaxf(m_run[r], mt[r]);
            alpha[r] = __expf(m_run[r] - mnew);
            m_run[r] = mnew;
        }
        float rs[4] = {0.f, 0.f, 0.f, 0.f};
#pragma unroll
        for (int nf = 0; nf < 4; nf++)
#pragma unroll
            for (int r = 0; r < 4; r++) {
                float p = __expf(sacc[nf][r] - m_run[r]);
                sacc[nf][r] = p;
                rs[r] += p;
            }
#pragma unroll
        for (int off = 1; off < 16; off <<= 1)
#pragma unroll
            for (int r = 0; r < 4; r++)
                rs[r] += __shfl_xor(rs[r], off, 64);
#pragma unroll
        for (int r = 0; r < 4; r++) l_run[r] = l_run[r] * alpha[r] + rs[r];
#pragma unroll
        for (int i = 0; i < 8; i++)
#pragma unroll
            for (int r = 0; r < 4; r++) o_acc[i][r] *= alpha[r];

        // P (C-layout) -> per-wave LDS (swizzled) to re-layout as A fragments
        u16* Pw = &Ps[w][0];
#pragma unroll
        for (int nf = 0; nf < 4; nf++) {
            int col = nf * 16 + (lane & 15);
#pragma unroll
            for (int r = 0; r < 4; r++) {
                int row = ((lane >> 4) << 2) + r;
                int slot = (col >> 3) ^ (row & 7);
                Pw[row * 64 + slot * 8 + (col & 7)] = f2b(sacc[nf][r]);
            }
        }

        // O += P V   (B-frags from swizzled V^T: contiguous along kv)
#pragma unroll
        for (int kk = 0; kk < 2; kk++) {
            int arow = lane & 15;
            int aslot = kk * 4 + (lane >> 4);
            s16x8 pa = *reinterpret_cast<const s16x8*>(
                (const char*)Pw + arow * 128 + ((aslot ^ (arow & 7)) << 4));
#pragma unroll
            for (int nf = 0; nf < 8; nf++) {
                int drow = nf * 16 + (lane & 15);
                int vslot = kk * 4 + (lane >> 4);
                s16x8 vf = *reinterpret_cast<const s16x8*>(
                    (const char*)Vs + drow * 128 + ((vslot ^ (drow & 7)) << 4));
                o_acc[nf] = __builtin_amdgcn_mfma_f32_16x16x32_bf16(pa, vf, o_acc[nf], 0, 0, 0);
            }
        }
    }

    // epilogue: O / l -> AO[b][q][h*128+d] bf16
#pragma unroll
    for (int nf = 0; nf < 8; nf++) {
        int d = nf * 16 + (lane & 15);
#pragma unroll
        for (int r = 0; r < 4; r++) {
            int q = q0 + ((lane >> 4) << 2) + r;
            float v = o_acc[nf][r] / l_run[r];
            AO[((size_t)b * SS + q) * HDN + h * HDIM + d] = f2b(v);
        }
    }
}

// ---------------------------------------------------------------------------
extern "C" void kernel_launch(void* const* d_in, const int* in_sizes, int n_in,
                              void* d_out, int out_size, void* d_ws, size_t ws_size,
                              hipStream_t stream) {
    (void)in_sizes; (void)n_in; (void)out_size; (void)ws_size;
    const float* hs   = (const float*)d_in[0];
    const float* cosp = (const float*)d_in[1];
    const float* sinp = (const float*)d_in[2];
    // d_in[3] attention_mask: exactly causal; applied analytically
    const float* Wq = (const float*)d_in[4];
    const float* bq = (const float*)d_in[5];
    const float* Wk = (const float*)d_in[6];
    const float* bk = (const float*)d_in[7];
    const float* Wv = (const float*)d_in[8];
    const float* bv = (const float*)d_in[9];
    const float* Wo = (const float*)d_in[10];
    float* out = (float*)d_out;

    char* ws = (char*)d_ws;
    size_t off = 0;
    u16* Xb   = (u16*)(ws + off); off += (size_t)MTOT * HDN * 2;        // 16.78 MB
    u16* Wqb  = (u16*)(ws + off); off += (size_t)HDN * HDN * 2;         //  8.39 MB
    u16* Wkb  = (u16*)(ws + off); off += (size_t)256 * HDN * 2;         //  1.05 MB
    u16* Wvb  = (u16*)(ws + off); off += (size_t)256 * HDN * 2;
    u16* Wob  = (u16*)(ws + off); off += (size_t)HDN * HDN * 2;
    float* Qpre = (float*)(ws + off); off += (size_t)MTOT * HDN * 4;    // 33.55 MB
    float* Kpre = (float*)(ws + off); off += (size_t)MTOT * 256 * 4;
    float* Vpre = (float*)(ws + off); off += (size_t)MTOT * 256 * 4;
    u16* Qb   = (u16*)(ws + off); off += (size_t)BB * NH * SS * HDIM * 2;
    u16* Kb   = (u16*)(ws + off); off += (size_t)BB * KVH * SS * HDIM * 2;
    u16* Vtb  = (u16*)(ws + off); off += (size_t)BB * KVH * HDIM * SS * 2;
    u16* AO   = (u16*)(ws + off); off += (size_t)MTOT * HDN * 2;

    // 1) converts
    cvt_f32_bf16<<<2048, 256, 0, stream>>>(hs, Xb, MTOT * HDN / 8);
    cvt_f32_bf16<<<2048, 256, 0, stream>>>(Wq, Wqb, HDN * HDN / 8);
    cvt_f32_bf16<<<256,  256, 0, stream>>>(Wk, Wkb, 256 * HDN / 8);
    cvt_f32_bf16<<<256,  256, 0, stream>>>(Wv, Wvb, 256 * HDN / 8);
    cvt_f32_bf16<<<2048, 256, 0, stream>>>(Wo, Wob, HDN * HDN / 8);

    // 2) projections (fp32 out + bias)
    gemm_bt<true><<<dim3(HDN / 128, MTOT / 128), 256, 0, stream>>>(Xb, Wqb, bq, Qpre, HDN, HDN);
    gemm_bt<true><<<dim3(256 / 128, MTOT / 128), 256, 0, stream>>>(Xb, Wkb, bk, Kpre, 256, HDN);
    gemm_bt<true><<<dim3(256 / 128, MTOT / 128), 256, 0, stream>>>(Xb, Wvb, bv, Vpre, 256, HDN);

    // 3) mRoPE -> bf16 head-major
    rope_kernel<<<(BB * SS * NH * 64) / 256, 256, 0, stream>>>(Qpre, cosp, sinp, Qb, NH);
    rope_kernel<<<(BB * SS * KVH * 64) / 256, 256, 0, stream>>>(Kpre, cosp, sinp, Kb, KVH);

    // 4) V -> bf16 transposed [B][KVH][D][S]
    vt_kernel<<<dim3(SS / 64, HDIM / 64, BB * KVH), 256, 0, stream>>>(Vpre, Vtb);

    // 5) causal GQA flash attention
    attn_kernel<<<dim3(SS / 64, NH, BB), 256, 0, stream>>>(Qb, Kb, Vtb, AO);

    // 6) output projection (no bias), fp32 out
    gemm_bt<false><<<dim3(HDN / 128, MTOT / 128), 256, 0, stream>>>(AO, Wob, nullptr, out, HDN, HDN);
}

// Round 2
// 239.789 us; speedup vs baseline: 1.7001x; 1.7001x over previous
//
#include <hip/hip_runtime.h>
#include <stdint.h>
#include <stddef.h>

#define HDN 2048
#define NH 16
#define KVH 2
#define HDIM 128
#define BB 2
#define SS 2048
#define MTOT 4096   // BB*SS
#define NQKV 2560   // 2048 + 256 + 256

typedef float f32x4 __attribute__((ext_vector_type(4)));
typedef short s16x8 __attribute__((ext_vector_type(8)));
typedef unsigned short u16;
typedef unsigned int u32;

__device__ __forceinline__ u16 f2b(float f) {
    u32 u = __builtin_bit_cast(u32, f);
    u += 0x7fffu + ((u >> 16) & 1u);
    return (u16)(u >> 16);
}

#define GLD_LDS16(src, dst) __builtin_amdgcn_global_load_lds( \
    (const __attribute__((address_space(1))) u32*)(src), \
    (__attribute__((address_space(3))) u32*)(dst), 16, 0, 0)

// ---------------- fp32 -> bf16 convert (8 elems/thread/iter) ----------------
__global__ void cvt_f32_bf16(const float* __restrict__ in, u16* __restrict__ out, int n8) {
    int stride = gridDim.x * blockDim.x;
    for (int idx = blockIdx.x * blockDim.x + threadIdx.x; idx < n8; idx += stride) {
        const float4* p = reinterpret_cast<const float4*>(in) + (size_t)idx * 2;
        float4 a = p[0], b = p[1];
        u16 u[8] = {f2b(a.x), f2b(a.y), f2b(a.z), f2b(a.w),
                    f2b(b.x), f2b(b.y), f2b(b.z), f2b(b.w)};
        reinterpret_cast<uint4*>(out)[idx] = *reinterpret_cast<uint4*>(u);
    }
}

// ---------------- GEMM: C[M,N] = A[M,K] * B[N,K]^T (+bias), fp32 out --------
// 128x128 tile, BK=32, 256 threads (4 waves, 2x2), 16x16x32 bf16 MFMA.
// BIASM: 0 = none, 1 = concat bias (bq | bk | bv at col 2048 / 2304).
template<int BIASM>
__global__ __launch_bounds__(256) void gemm_bt(
    const u16* __restrict__ A, const u16* __restrict__ B,
    const float* __restrict__ b0, const float* __restrict__ b1,
    const float* __restrict__ b2, float* __restrict__ C,
    int N, int K)
{
    const int tid = threadIdx.x;
    const int lane = tid & 63;
    const int w = tid >> 6;
    const int wm = w >> 1, wn = w & 1;
    const int bm = blockIdx.y, bn = blockIdx.x;

    __shared__ u16 As[128 * 32];
    __shared__ u16 Bs[128 * 32];

    f32x4 acc[4][4];
#pragma unroll
    for (int i = 0; i < 4; i++)
#pragma unroll
        for (int j = 0; j < 4; j++)
            acc[i][j] = (f32x4){0.f, 0.f, 0.f, 0.f};

    int srow[2], scol[2], sdst[2];
#pragma unroll
    for (int i = 0; i < 2; i++) {
        int o = w * 128 + i * 64 + lane;      // 16B slot index in [0,512)
        int r = o >> 2, s = o & 3;
        srow[i] = r;
        scol[i] = (s ^ ((r >> 1) & 3)) * 8;   // pre-swizzled source col (elems)
        sdst[i] = (w * 128 + i * 64) * 8;     // wave-uniform dest (u16 units)
    }

    const u16* Ab = A + (size_t)bm * 128 * K;
    const u16* Bb = B + (size_t)bn * 128 * K;

    int a_off[4], b_off[4];
#pragma unroll
    for (int f = 0; f < 4; f++) {
        int ra = wm * 64 + f * 16 + (lane & 15);
        a_off[f] = ra * 64 + (((lane >> 4) ^ ((ra >> 1) & 3)) << 4);
        int rb = wn * 64 + f * 16 + (lane & 15);
        b_off[f] = rb * 64 + (((lane >> 4) ^ ((rb >> 1) & 3)) << 4);
    }

    const int kiters = K >> 5;
    for (int kt = 0; kt < kiters; kt++) {
        __syncthreads();
        const int k0 = kt * 32;
#pragma unroll
        for (int i = 0; i < 2; i++) {
            GLD_LDS16(Ab + (size_t)srow[i] * K + k0 + scol[i], As + sdst[i]);
            GLD_LDS16(Bb + (size_t)srow[i] * K + k0 + scol[i], Bs + sdst[i]);
        }
        __syncthreads();
        s16x8 af[4], bfv[4];
#pragma unroll
        for (int f = 0; f < 4; f++) {
            af[f]  = *reinterpret_cast<const s16x8*>((const char*)As + a_off[f]);
            bfv[f] = *reinterpret_cast<const s16x8*>((const char*)Bs + b_off[f]);
        }
#pragma unroll
        for (int mf = 0; mf < 4; mf++)
#pragma unroll
            for (int nf = 0; nf < 4; nf++)
                acc[mf][nf] = __builtin_amdgcn_mfma_f32_16x16x32_bf16(
                    af[mf], bfv[nf], acc[mf][nf], 0, 0, 0);
    }

#pragma unroll
    for (int nf = 0; nf < 4; nf++) {
        int col = bn * 128 + wn * 64 + nf * 16 + (lane & 15);
        float bias = 0.0f;
        if (BIASM == 1)
            bias = (col < 2048) ? b0[col] : (col < 2304 ? b1[col - 2048] : b2[col - 2304]);
#pragma unroll
        for (int mf = 0; mf < 4; mf++) {
            int row0 = bm * 128 + wm * 64 + mf * 16 + ((lane >> 4) << 2);
#pragma unroll
            for (int r = 0; r < 4; r++)
                C[(size_t)(row0 + r) * N + col] = acc[mf][nf][r] + bias;
        }
    }
}

// ---------------- mRoPE: fp32 in [B*S][rowstride] -> bf16 [B][nh][S][128] ---
// mul folds attention scale*log2e into Q.
__global__ void rope_kernel(const float* __restrict__ pre, int rowstride,
                            const float* __restrict__ cosp,
                            const float* __restrict__ sinp,
                            u16* __restrict__ out, int nheads, float mul)
{
    int idx = blockIdx.x * blockDim.x + threadIdx.x; // d (64), then h, then b*s
    int total = BB * SS * nheads * 64;
    if (idx >= total) return;
    int d = idx & 63;
    int h = (idx >> 6) % nheads;
    int bs = idx / (64 * nheads);
    int b = bs / SS, s = bs % SS;
    int strm = (d < 16) ? 0 : (d < 40 ? 1 : 2);   // MROPE_SECTION [16,24,24]
    size_t cbase = ((size_t)(strm * BB + b) * SS + s) * HDIM;
    float c1 = cosp[cbase + d],      s1 = sinp[cbase + d];
    float c2 = cosp[cbase + d + 64], s2 = sinp[cbase + d + 64];
    size_t qbase = (size_t)bs * rowstride + h * HDIM;
    float q1 = pre[qbase + d], q2 = pre[qbase + d + 64];
    float o1 = (q1 * c1 - q2 * s1) * mul;   // rotate_half: [-x2, x1]
    float o2 = (q2 * c2 + q1 * s2) * mul;
    size_t obase = (((size_t)b * nheads + h) * SS + s) * HDIM;
    out[obase + d]      = f2b(o1);
    out[obase + d + 64] = f2b(o2);
}

// ---------------- V: fp32 strided -> bf16 V^T [B][KVH][128][S] --------------
__global__ void vt_kernel(const float* __restrict__ src, int rowstride,
                          u16* __restrict__ Vt)
{
    __shared__ float tile[64][65];
    int st = blockIdx.x, dt = blockIdx.y, bk = blockIdx.z;
    int b = bk / KVH, kv = bk % KVH;
    int t = threadIdx.x;
    int r = t >> 2, c0 = (t & 3) * 16;
#pragma unroll
    for (int j = 0; j < 16; j++) {
        int s = st * 64 + r, d = dt * 64 + c0 + j;
        tile[r][c0 + j] = src[(size_t)(b * SS + s) * rowstride + kv * HDIM + d];
    }
    __syncthreads();
#pragma unroll
    for (int j = 0; j < 16; j++) {
        int d = dt * 64 + r, s = st * 64 + c0 + j;
        Vt[((size_t)(b * KVH + kv) * HDIM + d) * SS + s] = f2b(tile[c0 + j][r]);
    }
}

// ---------------- Flash attention, causal, GQA (swapped-operand form) -------
// grid (16, NH, B): block bx handles q-tiles {bx, 31-bx} (33 kv-tiles, uniform).
// 4 waves x 16 q-rows. S^T = mfma(K,Q): lane owns q = lane&15, kv = nf*16+4g+r.
// O^T = mfma(V^T, P^T): lane owns q = lane&15, d = df*16+4g+r.
__global__ __launch_bounds__(256) void attn_kernel(
    const u16* __restrict__ Qb,  // [B][NH][S][128], pre-scaled by scale*log2e
    const u16* __restrict__ Kb,  // [B][KVH][S][128]
    const u16* __restrict__ Vt,  // [B][KVH][128][S]
    u16* __restrict__ AO)        // [B][S][NH*128]
{
    const int pr = blockIdx.x, h = blockIdx.y, b = blockIdx.z;
    const int kvh = h >> 3;      // h / (NH/KVH)
    const int tid = threadIdx.x, lane = tid & 63, w = tid >> 6;
    const int g = lane >> 4, ql = lane & 15;

    __shared__ u16 Ks[64 * 128];   // rows=kv (256B,16 slots), swz slot^(kv&7)
    __shared__ u16 Vs[128 * 64];   // rows=d  (128B, 8 slots), swz slot^(d&7)
    __shared__ u16 Ps[4][16 * 64]; // per-wave P[q][kv], 8B slots, swz s^((q&7)<<1)

    const u16* Kbase = Kb + ((size_t)b * KVH + kvh) * SS * HDIM;
    const u16* Vbase = Vt + ((size_t)b * KVH + kvh) * HDIM * (size_t)SS;

    int k_r[4], k_c[4], v_r[4], v_c[4], sdst[4];
#pragma unroll
    for (int i = 0; i < 4; i++) {
        int o = w * 256 + i * 64 + lane;       // 16B slots in [0,1024)
        int r = o >> 4, s = o & 15;            // K tile: 16 slots/row
        k_r[i] = r; k_c[i] = (s ^ (r & 7)) * 8;
        int r2 = o >> 3, s2 = o & 7;           // V tile: 8 slots/row
        v_r[i] = r2; v_c[i] = (s2 ^ (r2 & 7)) * 8;
        sdst[i] = (w * 256 + i * 64) * 8;      // wave-uniform dest (u16 units)
    }

    for (int half = 0; half < 2; half++) {
        const int qt = half ? (31 - pr) : pr;
        const int qg = qt * 64 + w * 16 + ql;  // this lane's q row

        const u16* Qrow = Qb + (((size_t)b * NH + h) * SS + qg) * HDIM;
        s16x8 qf[4];
#pragma unroll
        for (int kk = 0; kk < 4; kk++)
            qf[kk] = *reinterpret_cast<const s16x8*>(Qrow + kk * 32 + g * 8);

        f32x4 oacc[8];
#pragma unroll
        for (int i = 0; i < 8; i++) oacc[i] = (f32x4){0.f, 0.f, 0.f, 0.f};
        float m_run = -1e30f, l_run = 0.0f;

        const int ntiles = qt + 1;
        for (int kt = 0; kt < ntiles; kt++) {
            __syncthreads();
            const size_t kvoff = (size_t)kt * 64;
#pragma unroll
            for (int i = 0; i < 4; i++) {
                GLD_LDS16(Kbase + (kvoff + k_r[i]) * HDIM + k_c[i], Ks + sdst[i]);
                GLD_LDS16(Vbase + (size_t)v_r[i] * SS + kvoff + v_c[i], Vs + sdst[i]);
            }
            __syncthreads();

            // S^T tile: 64 kv x 16 q
            f32x4 sacc[4];
#pragma unroll
            for (int nf = 0; nf < 4; nf++) sacc[nf] = (f32x4){0.f, 0.f, 0.f, 0.f};
#pragma unroll
            for (int nf = 0; nf < 4; nf++) {
                const int krow = nf * 16 + ql;
                const char* Krow = (const char*)Ks + krow * 256;
#pragma unroll
                for (int kk = 0; kk < 4; kk++) {
                    s16x8 kf = *reinterpret_cast<const s16x8*>(
                        Krow + (((kk * 4 + g) ^ (krow & 7)) << 4));
                    sacc[nf] = __builtin_amdgcn_mfma_f32_16x16x32_bf16(
                        kf, qf[kk], sacc[nf], 0, 0, 0);
                }
            }

            if (kt == qt) {  // diagonal tile: causal mask
#pragma unroll
                for (int nf = 0; nf < 4; nf++)
#pragma unroll
                    for (int r = 0; r < 4; r++) {
                        int kv = kt * 64 + nf * 16 + 4 * g + r;
                        if (kv > qg) sacc[nf][r] = -1e30f;
                    }
            }

            // in-lane max over 16 + 2 shuffles across the 4 kv-groups
            float mt = fmaxf(fmaxf(fmaxf(sacc[0][0], sacc[0][1]), fmaxf(sacc[0][2], sacc[0][3])),
                             fmaxf(fmaxf(sacc[1][0], sacc[1][1]), fmaxf(sacc[1][2], sacc[1][3])));
            mt = fmaxf(mt, fmaxf(fmaxf(fmaxf(sacc[2][0], sacc[2][1]), fmaxf(sacc[2][2], sacc[2][3])),
                                 fmaxf(fmaxf(sacc[3][0], sacc[3][1]), fmaxf(sacc[3][2], sacc[3][3]))));
            mt = fmaxf(mt, __shfl_xor(mt, 16, 64));
            mt = fmaxf(mt, __shfl_xor(mt, 32, 64));

            // T13 defer-max: skip rescale while max growth <= 8 (log2 units)
            if (!__all(mt - m_run <= 8.0f)) {
                float mnew = fmaxf(m_run, mt);
                float alpha = exp2f(m_run - mnew);
                m_run = mnew;
                l_run *= alpha;
#pragma unroll
                for (int df = 0; df < 8; df++)
#pragma unroll
                    for (int r = 0; r < 4; r++) oacc[df][r] *= alpha;
            }

            float rs = 0.0f;
            uint2 pk[4];
#pragma unroll
            for (int nf = 0; nf < 4; nf++) {
                float p0 = exp2f(sacc[nf][0] - m_run);
                float p1 = exp2f(sacc[nf][1] - m_run);
                float p2 = exp2f(sacc[nf][2] - m_run);
                float p3 = exp2f(sacc[nf][3] - m_run);
                rs += (p0 + p1) + (p2 + p3);
                pk[nf].x = (u32)f2b(p0) | ((u32)f2b(p1) << 16);
                pk[nf].y = (u32)f2b(p2) | ((u32)f2b(p3) << 16);
            }
            rs += __shfl_xor(rs, 16, 64);
            rs += __shfl_xor(rs, 32, 64);
            l_run += rs;

            // P[q][kv] -> per-wave LDS (8B-slot XOR swizzle), 4x ds_write_b64
            char* Pw = (char*)&Ps[w][0];
#pragma unroll
            for (int nf = 0; nf < 4; nf++) {
                int s = nf * 4 + g;
                *reinterpret_cast<uint2*>(Pw + ql * 128 + ((s ^ ((ql & 7) << 1)) << 3)) = pk[nf];
            }

            // O^T += V^T * P^T
#pragma unroll
            for (int kk = 0; kk < 2; kk++) {
                int s0 = (kk * 8 + 2 * g) ^ ((ql & 7) << 1);
                s16x8 pf = *reinterpret_cast<const s16x8*>(Pw + ql * 128 + (s0 << 3));
#pragma unroll
                for (int df = 0; df < 8; df++) {
                    int vrow = df * 16 + ql;
                    s16x8 vf = *reinterpret_cast<const s16x8*>(
                        (const char*)Vs + vrow * 128 + (((kk * 4 + g) ^ (vrow & 7)) << 4));
                    oacc[df] = __builtin_amdgcn_mfma_f32_16x16x32_bf16(
                        vf, pf, oacc[df], 0, 0, 0);
                }
            }
        }

        // epilogue: lane owns q=qg, d = df*16+4g+r -> 8B packed stores
        float invl = 1.0f / l_run;
        u16* Ao = AO + ((size_t)b * SS + qg) * HDN + h * HDIM;
#pragma unroll
        for (int df = 0; df < 8; df++) {
            uint2 val;
            val.x = (u32)f2b(oacc[df][0] * invl) | ((u32)f2b(oacc[df][1] * invl) << 16);
            val.y = (u32)f2b(oacc[df][2] * invl) | ((u32)f2b(oacc[df][3] * invl) << 16);
            *reinterpret_cast<uint2*>(Ao + df * 16 + 4 * g) = val;
        }
    }
}

// ---------------------------------------------------------------------------
extern "C" void kernel_launch(void* const* d_in, const int* in_sizes, int n_in,
                              void* d_out, int out_size, void* d_ws, size_t ws_size,
                              hipStream_t stream) {
    (void)in_sizes; (void)n_in; (void)out_size; (void)ws_size;
    const float* hs   = (const float*)d_in[0];
    const float* cosp = (const float*)d_in[1];
    const float* sinp = (const float*)d_in[2];
    // d_in[3] attention_mask: exactly causal; applied analytically
    const float* Wq = (const float*)d_in[4];
    const float* bq = (const float*)d_in[5];
    const float* Wk = (const float*)d_in[6];
    const float* bk = (const float*)d_in[7];
    const float* Wv = (const float*)d_in[8];
    const float* bv = (const float*)d_in[9];
    const float* Wo = (const float*)d_in[10];
    float* out = (float*)d_out;

    char* ws = (char*)d_ws;
    size_t off = 0;
    u16* Xb     = (u16*)(ws + off); off += (size_t)MTOT * HDN * 2;       // 16.8 MB
    u16* Wall   = (u16*)(ws + off); off += (size_t)NQKV * HDN * 2;       // 10.5 MB
    u16* Wob    = (u16*)(ws + off); off += (size_t)HDN * HDN * 2;        //  8.4 MB
    float* QKVp = (float*)(ws + off); off += (size_t)MTOT * NQKV * 4;    // 41.9 MB
    u16* Qb     = (u16*)(ws + off); off += (size_t)BB * NH * SS * HDIM * 2;
    u16* Kb     = (u16*)(ws + off); off += (size_t)BB * KVH * SS * HDIM * 2;
    u16* Vtb    = (u16*)(ws + off); off += (size_t)BB * KVH * HDIM * SS * 2;
    u16* AO     = (u16*)(ws + off); off += (size_t)MTOT * HDN * 2;

    // 1) converts (Wq|Wk|Wv row-concatenated into one [2560][2048] buffer)
    cvt_f32_bf16<<<2048, 256, 0, stream>>>(hs, Xb, MTOT * HDN / 8);
    cvt_f32_bf16<<<2048, 256, 0, stream>>>(Wq, Wall, HDN * HDN / 8);
    cvt_f32_bf16<<<256,  256, 0, stream>>>(Wk, Wall + (size_t)HDN * HDN, 256 * HDN / 8);
    cvt_f32_bf16<<<256,  256, 0, stream>>>(Wv, Wall + (size_t)(HDN + 256) * HDN, 256 * HDN / 8);
    cvt_f32_bf16<<<2048, 256, 0, stream>>>(Wo, Wob, HDN * HDN / 8);

    // 2) fused QKV projection -> fp32 [4096][2560] (+concat bias)
    gemm_bt<1><<<dim3(NQKV / 128, MTOT / 128), 256, 0, stream>>>(
        Xb, Wall, bq, bk, bv, QKVp, NQKV, HDN);

    // 3) mRoPE -> bf16 head-major; Q pre-scaled by 1/sqrt(D)*log2(e)
    const float qmul = 0.08838834764831845f * 1.4426950408889634f;
    rope_kernel<<<(BB * SS * NH * 64) / 256, 256, 0, stream>>>(
        QKVp, NQKV, cosp, sinp, Qb, NH, qmul);
    rope_kernel<<<(BB * SS * KVH * 64) / 256, 256, 0, stream>>>(
        QKVp + HDN, NQKV, cosp, sinp, Kb, KVH, 1.0f);

    // 4) V -> bf16 transposed [B][KVH][128][S]
    vt_kernel<<<dim3(SS / 64, HDIM / 64, BB * KVH), 256, 0, stream>>>(
        QKVp + HDN + 256, NQKV, Vtb);

    // 5) causal GQA flash attention (pair-balanced grid)
    attn_kernel<<<dim3(16, NH, BB), 256, 0, stream>>>(Qb, Kb, Vtb, AO);

    // 6) output projection (no bias), fp32 out
    gemm_bt<0><<<dim3(HDN / 128, MTOT / 128), 256, 0, stream>>>(
        AO, Wob, nullptr, nullptr, nullptr, out, HDN, HDN);
}

// Round 3
// 226.607 us; speedup vs baseline: 1.7990x; 1.0582x over previous
//
#include <hip/hip_runtime.h>
#include <stdint.h>
#include <stddef.h>

#define HDN 2048
#define NH 16
#define KVH 2
#define HDIM 128
#define BB 2
#define SS 2048
#define MTOT 4096   // BB*SS
#define NQKV 2560   // 2048 + 256 + 256

typedef float f32x4 __attribute__((ext_vector_type(4)));
typedef short s16x8 __attribute__((ext_vector_type(8)));
typedef unsigned short u16;
typedef unsigned int u32;

__device__ __forceinline__ u16 f2b(float f) {
    u32 u = __builtin_bit_cast(u32, f);
    u += 0x7fffu + ((u >> 16) & 1u);
    return (u16)(u >> 16);
}
__device__ __forceinline__ float b2f(u16 u) {
    return __builtin_bit_cast(float, (u32)u << 16);
}
__device__ __forceinline__ u32 cvtpk(float lo, float hi) {
    u32 r;
    asm("v_cvt_pk_bf16_f32 %0, %1, %2" : "=v"(r) : "v"(lo), "v"(hi));
    return r;
}
__device__ __forceinline__ float fmax3(float a, float b, float c) {
    return fmaxf(fmaxf(a, b), c);
}

#define GLD_LDS16(src, dst) __builtin_amdgcn_global_load_lds( \
    (const __attribute__((address_space(1))) u32*)(src), \
    (__attribute__((address_space(3))) u32*)(dst), 16, 0, 0)

// ---------------- fp32 -> bf16 convert (8 elems/thread/iter) ----------------
__global__ void cvt_f32_bf16(const float* __restrict__ in, u16* __restrict__ out, int n8) {
    int stride = gridDim.x * blockDim.x;
    for (int idx = blockIdx.x * blockDim.x + threadIdx.x; idx < n8; idx += stride) {
        const float4* p = reinterpret_cast<const float4*>(in) + (size_t)idx * 2;
        float4 a = p[0], b = p[1];
        u16 u[8] = {f2b(a.x), f2b(a.y), f2b(a.z), f2b(a.w),
                    f2b(b.x), f2b(b.y), f2b(b.z), f2b(b.w)};
        reinterpret_cast<uint4*>(out)[idx] = *reinterpret_cast<uint4*>(u);
    }
}

// ---------------- GEMM: C[M,N] = A[M,K] * B[N,K]^T (+bias) ------------------
// 128x128 tile, BK=32, 256 threads (4 waves, 2x2), 16x16x32 bf16 MFMA.
// BIASM: 0 = none, 1 = concat bias (bq | bk | bv at col 2048 / 2304).
// CT: float or u16 (bf16) output.
template<int BIASM, typename CT>
__global__ __launch_bounds__(256) void gemm_bt(
    const u16* __restrict__ A, const u16* __restrict__ B,
    const float* __restrict__ b0, const float* __restrict__ b1,
    const float* __restrict__ b2, CT* __restrict__ C,
    int N, int K)
{
    const int tid = threadIdx.x;
    const int lane = tid & 63;
    const int w = tid >> 6;
    const int wm = w >> 1, wn = w & 1;

    // XCD-aware bijective swizzle (nwg % 8 == 0 for all our grids)
    const int gx = gridDim.x;
    int lin = blockIdx.y * gx + blockIdx.x;
    const int cpx = (gx * gridDim.y) >> 3;
    lin = (lin & 7) * cpx + (lin >> 3);
    const int bn = lin % gx;
    const int bm = lin / gx;

    __shared__ u16 As[128 * 32];
    __shared__ u16 Bs[128 * 32];

    f32x4 acc[4][4];
#pragma unroll
    for (int i = 0; i < 4; i++)
#pragma unroll
        for (int j = 0; j < 4; j++)
            acc[i][j] = (f32x4){0.f, 0.f, 0.f, 0.f};

    int srow[2], scol[2], sdst[2];
#pragma unroll
    for (int i = 0; i < 2; i++) {
        int o = w * 128 + i * 64 + lane;      // 16B slot index in [0,512)
        int r = o >> 2, s = o & 3;
        srow[i] = r;
        scol[i] = (s ^ ((r >> 1) & 3)) * 8;   // pre-swizzled source col (elems)
        sdst[i] = (w * 128 + i * 64) * 8;     // wave-uniform dest (u16 units)
    }

    const u16* Ab = A + (size_t)bm * 128 * K;
    const u16* Bb = B + (size_t)bn * 128 * K;

    int a_off[4], b_off[4];
#pragma unroll
    for (int f = 0; f < 4; f++) {
        int ra = wm * 64 + f * 16 + (lane & 15);
        a_off[f] = ra * 64 + (((lane >> 4) ^ ((ra >> 1) & 3)) << 4);
        int rb = wn * 64 + f * 16 + (lane & 15);
        b_off[f] = rb * 64 + (((lane >> 4) ^ ((rb >> 1) & 3)) << 4);
    }

    const int kiters = K >> 5;
    for (int kt = 0; kt < kiters; kt++) {
        __syncthreads();
        const int k0 = kt * 32;
#pragma unroll
        for (int i = 0; i < 2; i++) {
            GLD_LDS16(Ab + (size_t)srow[i] * K + k0 + scol[i], As + sdst[i]);
            GLD_LDS16(Bb + (size_t)srow[i] * K + k0 + scol[i], Bs + sdst[i]);
        }
        __syncthreads();
        s16x8 af[4], bfv[4];
#pragma unroll
        for (int f = 0; f < 4; f++) {
            af[f]  = *reinterpret_cast<const s16x8*>((const char*)As + a_off[f]);
            bfv[f] = *reinterpret_cast<const s16x8*>((const char*)Bs + b_off[f]);
        }
#pragma unroll
        for (int mf = 0; mf < 4; mf++)
#pragma unroll
            for (int nf = 0; nf < 4; nf++)
                acc[mf][nf] = __builtin_amdgcn_mfma_f32_16x16x32_bf16(
                    af[mf], bfv[nf], acc[mf][nf], 0, 0, 0);
    }

#pragma unroll
    for (int nf = 0; nf < 4; nf++) {
        int col = bn * 128 + wn * 64 + nf * 16 + (lane & 15);
        float bias = 0.0f;
        if (BIASM == 1)
            bias = (col < 2048) ? b0[col] : (col < 2304 ? b1[col - 2048] : b2[col - 2304]);
#pragma unroll
        for (int mf = 0; mf < 4; mf++) {
            int row0 = bm * 128 + wm * 64 + mf * 16 + ((lane >> 4) << 2);
#pragma unroll
            for (int r = 0; r < 4; r++) {
                float v = acc[mf][nf][r] + bias;
                if constexpr (__is_same(CT, u16))
                    C[(size_t)(row0 + r) * N + col] = f2b(v);
                else
                    C[(size_t)(row0 + r) * N + col] = v;
            }
        }
    }
}

// ---------------- mRoPE: bf16 in [B*S][rowstride] -> bf16 [B][nh][S][128] ---
// mul folds attention scale*log2e into Q.
__global__ void rope_kernel(const u16* __restrict__ pre, int rowstride,
                            const float* __restrict__ cosp,
                            const float* __restrict__ sinp,
                            u16* __restrict__ out, int nheads, float mul)
{
    int idx = blockIdx.x * blockDim.x + threadIdx.x; // d (64), then h, then b*s
    int total = BB * SS * nheads * 64;
    if (idx >= total) return;
    int d = idx & 63;
    int h = (idx >> 6) % nheads;
    int bs = idx / (64 * nheads);
    int b = bs / SS, s = bs % SS;
    int strm = (d < 16) ? 0 : (d < 40 ? 1 : 2);   // MROPE_SECTION [16,24,24]
    size_t cbase = ((size_t)(strm * BB + b) * SS + s) * HDIM;
    float c1 = cosp[cbase + d],      s1 = sinp[cbase + d];
    float c2 = cosp[cbase + d + 64], s2 = sinp[cbase + d + 64];
    size_t qbase = (size_t)bs * rowstride + h * HDIM;
    float q1 = b2f(pre[qbase + d]), q2 = b2f(pre[qbase + d + 64]);
    float o1 = (q1 * c1 - q2 * s1) * mul;   // rotate_half: [-x2, x1]
    float o2 = (q2 * c2 + q1 * s2) * mul;
    size_t obase = (((size_t)b * nheads + h) * SS + s) * HDIM;
    out[obase + d]      = f2b(o1);
    out[obase + d + 64] = f2b(o2);
}

// ---------------- V: bf16 strided -> bf16 V^T [B][KVH][128][S] --------------
__global__ void vt_kernel(const u16* __restrict__ src, int rowstride,
                          u16* __restrict__ Vt)
{
    __shared__ u16 tile[64][80];
    int st = blockIdx.x, dt = blockIdx.y, bk = blockIdx.z;
    int b = bk / KVH, kv = bk % KVH;
    int t = threadIdx.x;
    int r = t >> 2, c0 = (t & 3) * 16;
    const u16* p = src + (size_t)(b * SS + st * 64 + r) * rowstride
                       + kv * HDIM + dt * 64 + c0;
    *reinterpret_cast<uint4*>(&tile[r][c0])     = *reinterpret_cast<const uint4*>(p);
    *reinterpret_cast<uint4*>(&tile[r][c0 + 8]) = *reinterpret_cast<const uint4*>(p + 8);
    __syncthreads();
    u16 tmp[16];
#pragma unroll
    for (int j = 0; j < 16; j++) tmp[j] = tile[c0 + j][r];
    u16* dst = Vt + (((size_t)(b * KVH + kv) * HDIM) + dt * 64 + r) * SS + st * 64 + c0;
    *reinterpret_cast<uint4*>(dst)     = *reinterpret_cast<uint4*>(&tmp[0]);
    *reinterpret_cast<uint4*>(dst + 8) = *reinterpret_cast<uint4*>(&tmp[8]);
}

// ---------------- Flash attention, causal, GQA (swapped-operand form) -------
// grid (16, NH, B): block bx handles q-tiles {bx, 31-bx} (33 kv-tiles, uniform).
// 4 waves x 16 q-rows. S^T = mfma(K,Q): lane owns q = lane&15, kv = nf*16+4g+r.
// O^T = mfma(V^T, P^T): lane owns q = lane&15, d = df*16+4g+r.
// 2-buffer K/V prefetch pipeline: STAGE(next) || compute(cur); vmcnt(0)+s_barrier.
__global__ __launch_bounds__(256, 2) void attn_kernel(
    const u16* __restrict__ Qb,  // [B][NH][S][128], pre-scaled by scale*log2e
    const u16* __restrict__ Kb,  // [B][KVH][S][128]
    const u16* __restrict__ Vt,  // [B][KVH][128][S]
    u16* __restrict__ AO)        // [B][S][NH*128]
{
    const int pr = blockIdx.x, h = blockIdx.y, b = blockIdx.z;
    const int kvh = h >> 3;      // h / (NH/KVH)
    const int tid = threadIdx.x, lane = tid & 63, w = tid >> 6;
    const int g = lane >> 4, ql = lane & 15;

    __shared__ u16 Ks[2][64 * 128];   // rows=kv (256B,16 slots), swz slot^(kv&7)
    __shared__ u16 Vs[2][128 * 64];   // rows=d  (128B, 8 slots), swz slot^(d&7)
    __shared__ u16 Ps[4][16 * 64];    // per-wave P[q][kv], 8B slots, swz s^((q&7)<<1)

    const u16* Kbase = Kb + ((size_t)b * KVH + kvh) * SS * HDIM;
    const u16* Vbase = Vt + ((size_t)b * KVH + kvh) * HDIM * (size_t)SS;

    int k_r[4], k_c[4], v_r[4], v_c[4], sdst[4];
#pragma unroll
    for (int i = 0; i < 4; i++) {
        int o = w * 256 + i * 64 + lane;       // 16B slots in [0,1024)
        int r = o >> 4, s = o & 15;            // K tile: 16 slots/row
        k_r[i] = r; k_c[i] = (s ^ (r & 7)) * 8;
        int r2 = o >> 3, s2 = o & 7;           // V tile: 8 slots/row
        v_r[i] = r2; v_c[i] = (s2 ^ (r2 & 7)) * 8;
        sdst[i] = (w * 256 + i * 64) * 8;      // wave-uniform dest (u16 units)
    }

#define STAGE(buf, kt) do {                                                    \
        const size_t kvo_ = (size_t)(kt) * 64;                                 \
        _Pragma("unroll")                                                      \
        for (int i_ = 0; i_ < 4; i_++) {                                       \
            GLD_LDS16(Kbase + (kvo_ + k_r[i_]) * HDIM + k_c[i_],               \
                      &Ks[buf][0] + sdst[i_]);                                 \
            GLD_LDS16(Vbase + (size_t)v_r[i_] * SS + kvo_ + v_c[i_],           \
                      &Vs[buf][0] + sdst[i_]);                                 \
        }                                                                      \
    } while (0)

    for (int half = 0; half < 2; half++) {
        const int qt = half ? (31 - pr) : pr;
        const int qg = qt * 64 + w * 16 + ql;  // this lane's q row

        const u16* Qrow = Qb + (((size_t)b * NH + h) * SS + qg) * HDIM;
        s16x8 qf[4];
#pragma unroll
        for (int kk = 0; kk < 4; kk++)
            qf[kk] = *reinterpret_cast<const s16x8*>(Qrow + kk * 32 + g * 8);

        f32x4 oacc[8];
#pragma unroll
        for (int i = 0; i < 8; i++) oacc[i] = (f32x4){0.f, 0.f, 0.f, 0.f};
        float m_run = -1e30f, l_run = 0.0f;

        const int ntiles = qt + 1;

        STAGE(0, 0);
        asm volatile("s_waitcnt vmcnt(0)" ::: "memory");
        __builtin_amdgcn_s_barrier();

        for (int kt = 0; kt < ntiles; kt++) {
            const int cur = kt & 1;
            if (kt + 1 < ntiles) STAGE(cur ^ 1, kt + 1);   // prefetch under compute

            // ---- S^T tile: 64 kv x 16 q ----
            f32x4 sacc[4];
#pragma unroll
            for (int nf = 0; nf < 4; nf++) sacc[nf] = (f32x4){0.f, 0.f, 0.f, 0.f};
            __builtin_amdgcn_s_setprio(1);
#pragma unroll
            for (int nf = 0; nf < 4; nf++) {
                const int krow = nf * 16 + ql;
                const char* Krow = (const char*)&Ks[cur][0] + krow * 256;
#pragma unroll
                for (int kk = 0; kk < 4; kk++) {
                    s16x8 kf = *reinterpret_cast<const s16x8*>(
                        Krow + (((kk * 4 + g) ^ (krow & 7)) << 4));
                    sacc[nf] = __builtin_amdgcn_mfma_f32_16x16x32_bf16(
                        kf, qf[kk], sacc[nf], 0, 0, 0);
                }
            }
            __builtin_amdgcn_s_setprio(0);

            if (kt == qt) {  // diagonal tile: causal mask
#pragma unroll
                for (int nf = 0; nf < 4; nf++)
#pragma unroll
                    for (int r = 0; r < 4; r++) {
                        int kv = kt * 64 + nf * 16 + 4 * g + r;
                        if (kv > qg) sacc[nf][r] = -1e30f;
                    }
            }

            // ---- row max: v_max3 tree + 2 shuffles across the 4 kv-groups ----
            float t0 = fmax3(sacc[0][0], sacc[0][1], sacc[0][2]);
            float t1 = fmax3(sacc[0][3], sacc[1][0], sacc[1][1]);
            float t2 = fmax3(sacc[1][2], sacc[1][3], sacc[2][0]);
            float t3 = fmax3(sacc[2][1], sacc[2][2], sacc[2][3]);
            float t4 = fmax3(sacc[3][0], sacc[3][1], sacc[3][2]);
            float mt = fmax3(fmax3(t0, t1, t2), fmaxf(t3, t4), sacc[3][3]);
            mt = fmaxf(mt, __shfl_xor(mt, 16, 64));
            mt = fmaxf(mt, __shfl_xor(mt, 32, 64));

            // T13 defer-max: skip rescale while max growth <= 8 (log2 units)
            if (!__all(mt - m_run <= 8.0f)) {
                float mnew = fmaxf(m_run, mt);
                float alpha = exp2f(m_run - mnew);
                m_run = mnew;
                l_run *= alpha;
#pragma unroll
                for (int df = 0; df < 8; df++)
#pragma unroll
                    for (int r = 0; r < 4; r++) oacc[df][r] *= alpha;
            }

            float rs = 0.0f;
            uint2 pk[4];
#pragma unroll
            for (int nf = 0; nf < 4; nf++) {
                float p0 = exp2f(sacc[nf][0] - m_run);
                float p1 = exp2f(sacc[nf][1] - m_run);
                float p2 = exp2f(sacc[nf][2] - m_run);
                float p3 = exp2f(sacc[nf][3] - m_run);
                rs += (p0 + p1) + (p2 + p3);
                pk[nf].x = cvtpk(p0, p1);
                pk[nf].y = cvtpk(p2, p3);
            }
            rs += __shfl_xor(rs, 16, 64);
            rs += __shfl_xor(rs, 32, 64);
            l_run += rs;

            // P[q][kv] -> per-wave LDS (8B-slot XOR swizzle), 4x ds_write_b64
            char* Pw = (char*)&Ps[w][0];
#pragma unroll
            for (int nf = 0; nf < 4; nf++) {
                int s = nf * 4 + g;
                *reinterpret_cast<uint2*>(Pw + ql * 128 + ((s ^ ((ql & 7) << 1)) << 3)) = pk[nf];
            }

            // ---- O^T += V^T * P^T ----
            __builtin_amdgcn_s_setprio(1);
#pragma unroll
            for (int kk = 0; kk < 2; kk++) {
                int s0 = (kk * 8 + 2 * g) ^ ((ql & 7) << 1);
                s16x8 pf = *reinterpret_cast<const s16x8*>(Pw + ql * 128 + (s0 << 3));
#pragma unroll
                for (int df = 0; df < 8; df++) {
                    int vrow = df * 16 + ql;
                    s16x8 vf = *reinterpret_cast<const s16x8*>(
                        (const char*)&Vs[cur][0] + vrow * 128 + (((kk * 4 + g) ^ (vrow & 7)) << 4));
                    oacc[df] = __builtin_amdgcn_mfma_f32_16x16x32_bf16(
                        vf, pf, oacc[df], 0, 0, 0);
                }
            }
            __builtin_amdgcn_s_setprio(0);

            // prefetch landed + everyone done reading cur
            asm volatile("s_waitcnt vmcnt(0)" ::: "memory");
            __builtin_amdgcn_s_barrier();
        }

        // epilogue: lane owns q=qg, d = df*16+4g+r -> 8B packed stores
        float invl = 1.0f / l_run;
        u16* Ao = AO + ((size_t)b * SS + qg) * HDN + h * HDIM;
#pragma unroll
        for (int df = 0; df < 8; df++) {
            uint2 val;
            val.x = cvtpk(oacc[df][0] * invl, oacc[df][1] * invl);
            val.y = cvtpk(oacc[df][2] * invl, oacc[df][3] * invl);
            *reinterpret_cast<uint2*>(Ao + df * 16 + 4 * g) = val;
        }
    }
#undef STAGE
}

// ---------------------------------------------------------------------------
extern "C" void kernel_launch(void* const* d_in, const int* in_sizes, int n_in,
                              void* d_out, int out_size, void* d_ws, size_t ws_size,
                              hipStream_t stream) {
    (void)in_sizes; (void)n_in; (void)out_size; (void)ws_size;
    const float* hs   = (const float*)d_in[0];
    const float* cosp = (const float*)d_in[1];
    const float* sinp = (const float*)d_in[2];
    // d_in[3] attention_mask: exactly causal; applied analytically
    const float* Wq = (const float*)d_in[4];
    const float* bq = (const float*)d_in[5];
    const float* Wk = (const float*)d_in[6];
    const float* bk = (const float*)d_in[7];
    const float* Wv = (const float*)d_in[8];
    const float* bv = (const float*)d_in[9];
    const float* Wo = (const float*)d_in[10];
    float* out = (float*)d_out;

    char* ws = (char*)d_ws;
    size_t off = 0;
    u16* Xb     = (u16*)(ws + off); off += (size_t)MTOT * HDN * 2;       // 16.8 MB
    u16* Wall   = (u16*)(ws + off); off += (size_t)NQKV * HDN * 2;       // 10.5 MB
    u16* Wob    = (u16*)(ws + off); off += (size_t)HDN * HDN * 2;        //  8.4 MB
    u16* QKVb   = (u16*)(ws + off); off += (size_t)MTOT * NQKV * 2;      // 21.0 MB
    u16* Qb     = (u16*)(ws + off); off += (size_t)BB * NH * SS * HDIM * 2;
    u16* Kb     = (u16*)(ws + off); off += (size_t)BB * KVH * SS * HDIM * 2;
    u16* Vtb    = (u16*)(ws + off); off += (size_t)BB * KVH * HDIM * SS * 2;
    u16* AO     = (u16*)(ws + off); off += (size_t)MTOT * HDN * 2;

    // 1) converts (Wq|Wk|Wv row-concatenated into one [2560][2048] buffer)
    cvt_f32_bf16<<<2048, 256, 0, stream>>>(hs, Xb, MTOT * HDN / 8);
    cvt_f32_bf16<<<2048, 256, 0, stream>>>(Wq, Wall, HDN * HDN / 8);
    cvt_f32_bf16<<<256,  256, 0, stream>>>(Wk, Wall + (size_t)HDN * HDN, 256 * HDN / 8);
    cvt_f32_bf16<<<256,  256, 0, stream>>>(Wv, Wall + (size_t)(HDN + 256) * HDN, 256 * HDN / 8);
    cvt_f32_bf16<<<2048, 256, 0, stream>>>(Wo, Wob, HDN * HDN / 8);

    // 2) fused QKV projection -> bf16 [4096][2560] (+concat bias)
    gemm_bt<1, u16><<<dim3(NQKV / 128, MTOT / 128), 256, 0, stream>>>(
        Xb, Wall, bq, bk, bv, QKVb, NQKV, HDN);

    // 3) mRoPE -> bf16 head-major; Q pre-scaled by 1/sqrt(D)*log2(e)
    const float qmul = 0.08838834764831845f * 1.4426950408889634f;
    rope_kernel<<<(BB * SS * NH * 64) / 256, 256, 0, stream>>>(
        QKVb, NQKV, cosp, sinp, Qb, NH, qmul);
    rope_kernel<<<(BB * SS * KVH * 64) / 256, 256, 0, stream>>>(
        QKVb + HDN, NQKV, cosp, sinp, Kb, KVH, 1.0f);

    // 4) V -> bf16 transposed [B][KVH][128][S]
    vt_kernel<<<dim3(SS / 64, HDIM / 64, BB * KVH), 256, 0, stream>>>(
        QKVb + HDN + 256, NQKV, Vtb);

    // 5) causal GQA flash attention (pair-balanced grid, prefetch pipeline)
    attn_kernel<<<dim3(16, NH, BB), 256, 0, stream>>>(Qb, Kb, Vtb, AO);

    // 6) output projection (no bias), fp32 out
    gemm_bt<0, float><<<dim3(HDN / 128, MTOT / 128), 256, 0, stream>>>(
        AO, Wob, nullptr, nullptr, nullptr, out, HDN, HDN);
}